// Round 3
// baseline (292.285 us; speedup 1.0000x reference)
//
#include <hip/hip_runtime.h>
#include <stdint.h>

#define L2E 1.44269504088896f

static __device__ __forceinline__ float wsum(float v) {
    #pragma unroll
    for (int m = 1; m < 64; m <<= 1) v += __shfl_xor(v, m, 64);
    return v;
}
static __device__ __forceinline__ float sigm(float x) {
    return 1.0f / (1.0f + __builtin_amdgcn_exp2f(-x * L2E));
}
static __device__ __forceinline__ float tanh_(float x) {
    const float ax = fabsf(x);
    const float t = __builtin_amdgcn_exp2f(-2.0f * ax * L2E);
    const float r = (1.0f - t) / (1.0f + t);
    return (x < 0.f) ? -r : r;
}

// ---------------------------------------------------------------------------
// Slot-side tail shared by init/update: LN(slot) -> q = sn@Wq*0.125 ->
// kq = Wk@q -> store gkq = ln_inp_g*kq, aux = (sum g*kq, sum b*kq).
// One wave per (b,s) row; lane = dim. All barriers are block-uniform.
// ---------------------------------------------------------------------------
static __device__ __forceinline__ void slot_ln_q_kq(
    float snv, int wv, int lane, int r,
    float* scr,                 // per-wave 64-float LDS scratch
    const float* wkT,           // block LDS: wkT[p*64+d] = Wk[d][p]
    const float* lsg, const float* lsb, const float* Wq,
    const float* lig, const float* lib,
    float* __restrict__ gkq, float* __restrict__ aux)
{
    const float mean = wsum(snv) * (1.0f / 64.0f);
    const float d = snv - mean;
    const float var = wsum(d * d) * (1.0f / 64.0f);
    const float rs = rsqrtf(var + 1e-5f);
    const float sn = d * rs * lsg[lane] + lsb[lane];
    __syncthreads();
    scr[lane] = sn;
    __syncthreads();
    float q = 0.f;
    #pragma unroll 8
    for (int i = 0; i < 64; ++i) q = fmaf(scr[i], Wq[i * 64 + lane], q);
    q *= 0.125f;                       // fold 1/sqrt(DP)
    __syncthreads();
    scr[lane] = q;
    __syncthreads();
    float kq = 0.f;
    #pragma unroll 8
    for (int p = 0; p < 64; ++p) kq = fmaf(wkT[p * 64 + lane], scr[p], kq);
    const float bk = wsum(lib[lane] * kq);
    const float gk = lig[lane] * kq;
    const float g1 = wsum(gk);
    gkq[r * 64 + lane] = gk;
    if (lane == 0) { aux[r * 2] = g1; aux[r * 2 + 1] = bk; }
}

// ---------------------------------------------------------------------------
// init: slots <- broadcast(slots_init); produce gkq/aux for iter 0.
// grid 112 x 256, one wave per (b,s).
// ---------------------------------------------------------------------------
__global__ __launch_bounds__(256) void init_kernel(
    const float* __restrict__ s0,
    const float* __restrict__ lsg, const float* __restrict__ lsb,
    const float* __restrict__ Wq,  const float* __restrict__ Wk,
    const float* __restrict__ lig, const float* __restrict__ lib,
    float* __restrict__ slots, float* __restrict__ gkq, float* __restrict__ aux)
{
    __shared__ float wkT[4096];
    __shared__ float scr[4][64];
    const int tid = threadIdx.x, lane = tid & 63, wv = tid >> 6;
    const int r = blockIdx.x * 4 + wv;          // 0..447
    const int s = r % 7;
    #pragma unroll
    for (int i = tid; i < 4096; i += 256) {
        const int d = i >> 6, p = i & 63;
        wkT[p * 64 + d] = Wk[i];
    }
    const float h = s0[s * 64 + lane];
    slots[r * 64 + lane] = h;
    __syncthreads();
    slot_ln_q_kq(h, wv, lane, r, &scr[wv][0], wkT, lsg, lsb, Wq, lig, lib, gkq, aux);
}

// ---------------------------------------------------------------------------
// attn (per iteration): per row n: raw-moment LN fold, logits vs gkq,
// softmax+eps; partials Y[b][chunk][s][d] (plain stores after in-LDS block
// reduce), zc[b][sub][s][2] = (Z,C) per 64-row subchunk. No global atomics.
// grid B*16 = 1024 blocks x 256; wave handles 64 rows.
// ---------------------------------------------------------------------------
__global__ __launch_bounds__(256) void attn_kernel(
    const float* __restrict__ x,
    const float* __restrict__ gkq, const float* __restrict__ aux,
    float* __restrict__ Y, float* __restrict__ zc)
{
    __shared__ float gkql[448];
    __shared__ float auxl[14];
    __shared__ float wsh[4][64][8];
    __shared__ float ybuf[4][448];
    const int tid = threadIdx.x, lane = tid & 63, wv = tid >> 6;
    const int b = blockIdx.x >> 4, chunk = blockIdx.x & 15;

    gkql[tid] = gkq[b * 448 + tid];
    { const int i2 = tid + 256; if (i2 < 448) gkql[i2] = gkq[b * 448 + i2]; }
    if (tid < 14) auxl[tid] = aux[b * 14 + tid];
    __syncthreads();

    // ---- Phase A: lane = row ----
    const int row = chunk * 256 + wv * 64 + lane;
    const float4* xr4 = (const float4*)(x + ((long)b * 4096 + row) * 64);
    float sum = 0.f, ss = 0.f;
    float acc[7] = {0.f, 0.f, 0.f, 0.f, 0.f, 0.f, 0.f};
    #pragma unroll
    for (int c = 0; c < 16; ++c) {
        const float4 f4 = xr4[c];
        const float f[4] = {f4.x, f4.y, f4.z, f4.w};
        #pragma unroll
        for (int j = 0; j < 4; ++j) { sum += f[j]; ss = fmaf(f[j], f[j], ss); }
        #pragma unroll
        for (int s = 0; s < 7; ++s) {
            #pragma unroll
            for (int j = 0; j < 4; ++j)
                acc[s] = fmaf(f[j], gkql[s * 64 + c * 4 + j], acc[s]);
        }
    }
    const float m   = sum * (1.0f / 64.0f);
    const float var = ss * (1.0f / 64.0f) - m * m;
    const float rs  = rsqrtf(var + 1e-5f);
    const float rsm = rs * m;
    float t[7];
    #pragma unroll
    for (int s = 0; s < 7; ++s)
        t[s] = fmaf(rs, acc[s], fmaf(-rsm, auxl[2 * s], auxl[2 * s + 1]));
    float mx = t[0];
    #pragma unroll
    for (int s = 1; s < 7; ++s) mx = fmaxf(mx, t[s]);
    float e[7], se = 0.f;
    #pragma unroll
    for (int s = 0; s < 7; ++s) {
        e[s] = __builtin_amdgcn_exp2f((t[s] - mx) * L2E);
        se += e[s];
    }
    const float inv = 1.0f / se;
    float w[7];
    #pragma unroll
    for (int s = 0; s < 7; ++s) w[s] = fmaf(e[s], inv, 1e-8f);

    const int sub = chunk * 4 + wv;             // 0..63 within batch b
    #pragma unroll
    for (int s = 0; s < 7; ++s) {
        const float csp = wsum(w[s]);
        const float zp  = wsum(w[s] * rsm);
        if (lane == 0) {
            float* z2 = &zc[(((long)b * 64 + sub) * 7 + s) * 2];
            z2[0] = zp; z2[1] = csp;
        }
        wsh[wv][lane][s] = w[s] * rs;
    }
    wsh[wv][lane][7] = 0.f;
    __syncthreads();

    // ---- Phase B: lane = (half, dim-pair); x re-read hits L1/L2 ----
    const int half = lane >> 5, dp = lane & 31;
    const float* xb = x + ((long)b * 4096 + chunk * 256 + wv * 64) * 64;
    float Yr[14];
    #pragma unroll
    for (int i = 0; i < 14; ++i) Yr[i] = 0.f;
    #pragma unroll 4
    for (int r2 = 0; r2 < 32; ++r2) {
        const int rr = r2 * 2 + half;
        const float4 p0 = *(const float4*)&wsh[wv][rr][0];
        const float4 p1 = *(const float4*)&wsh[wv][rr][4];
        const float2 xv = *(const float2*)(xb + rr * 64 + dp * 2);
        const float ps[7] = {p0.x, p0.y, p0.z, p0.w, p1.x, p1.y, p1.z};
        #pragma unroll
        for (int s = 0; s < 7; ++s) {
            Yr[2 * s]     = fmaf(ps[s], xv.x, Yr[2 * s]);
            Yr[2 * s + 1] = fmaf(ps[s], xv.y, Yr[2 * s + 1]);
        }
    }
    #pragma unroll
    for (int i = 0; i < 14; ++i) Yr[i] += __shfl_xor(Yr[i], 32, 64);
    if (lane < 32) {
        #pragma unroll
        for (int s = 0; s < 7; ++s) {
            ybuf[wv][s * 64 + dp * 2]     = Yr[2 * s];
            ybuf[wv][s * 64 + dp * 2 + 1] = Yr[2 * s + 1];
        }
    }
    __syncthreads();
    for (int i = tid; i < 448; i += 256) {
        Y[((long)b * 16 + chunk) * 448 + i] =
            ybuf[0][i] + ybuf[1][i] + ybuf[2][i] + ybuf[3][i];
    }
}

// ---------------------------------------------------------------------------
// update (per iteration): reduce partials -> A = g*(Y-Z)+b*C -> u=(A@Wv)/C ->
// GRU -> MLP -> slots; then next-iter LN+q+kq or final fp32 store.
// grid 112 x 256, one wave per (b,s).
// ---------------------------------------------------------------------------
__global__ __launch_bounds__(256) void update_kernel(
    const float* __restrict__ Y, const float* __restrict__ zc,
    float* __restrict__ slots,
    const float* __restrict__ Wv,
    const float* __restrict__ wih, const float* __restrict__ whh,
    const float* __restrict__ bih, const float* __restrict__ bhh,
    const float* __restrict__ w1,  const float* __restrict__ b1,
    const float* __restrict__ w2,  const float* __restrict__ b2,
    const float* __restrict__ lsg, const float* __restrict__ lsb,
    const float* __restrict__ Wq,  const float* __restrict__ Wk,
    const float* __restrict__ lig, const float* __restrict__ lib,
    float* __restrict__ gkq, float* __restrict__ aux,
    float* __restrict__ out, int last)
{
    __shared__ float wkT[4096];
    __shared__ float scr[4][64];
    __shared__ float ub[4][64], hb[4][64], mb[4][128];
    const int tid = threadIdx.x, lane = tid & 63, wv = tid >> 6;
    const int r = blockIdx.x * 4 + wv;          // 0..447
    const int b = r / 7, s = r - b * 7;

    #pragma unroll
    for (int i = tid; i < 4096; i += 256) {
        const int d = i >> 6, p = i & 63;
        wkT[p * 64 + d] = Wk[i];
    }

    // reduce Z,C over the 64 subchunks (lane = subchunk)
    const float2 zp = *(const float2*)&zc[(((long)b * 64 + lane) * 7 + s) * 2];
    const float Zv = wsum(zp.x);
    const float Cv = wsum(zp.y);
    // reduce Y over the 16 chunk partials
    float Yd = 0.f;
    #pragma unroll
    for (int c = 0; c < 16; ++c)
        Yd += Y[((long)b * 16 + c) * 448 + s * 64 + lane];

    const float aoc = (lig[lane] * (Yd - Zv) + lib[lane] * Cv) / Cv;
    scr[wv][lane] = aoc;
    __syncthreads();                     // covers wkT + scr

    float u = 0.f;
    #pragma unroll 8
    for (int i = 0; i < 64; ++i) u = fmaf(scr[wv][i], Wv[i * 64 + lane], u);

    const float h = slots[r * 64 + lane];
    ub[wv][lane] = u; hb[wv][lane] = h;
    __syncthreads();

    float gi[3], gh[3];
    #pragma unroll
    for (int g = 0; g < 3; ++g) {
        const int j = g * 64 + lane;
        float a1 = bih[j], a2 = bhh[j];
        const float* wi = wih + j * 64;
        const float* wh = whh + j * 64;
        #pragma unroll 8
        for (int i = 0; i < 64; ++i) {
            a1 = fmaf(ub[wv][i], wi[i], a1);
            a2 = fmaf(hb[wv][i], wh[i], a2);
        }
        gi[g] = a1; gh[g] = a2;
    }
    const float rr = sigm(gi[0] + gh[0]);
    const float zz = sigm(gi[1] + gh[1]);
    const float nn = tanh_(gi[2] + rr * gh[2]);
    const float hn = (1.f - zz) * nn + zz * h;

    __syncthreads();
    ub[wv][lane] = hn;
    __syncthreads();
    float m0 = b1[lane], m1 = b1[64 + lane];
    #pragma unroll 8
    for (int i = 0; i < 64; ++i) {
        const float hv = ub[wv][i];
        m0 = fmaf(hv, w1[i * 128 + lane], m0);
        m1 = fmaf(hv, w1[i * 128 + 64 + lane], m1);
    }
    m0 = fmaxf(m0, 0.f); m1 = fmaxf(m1, 0.f);
    mb[wv][lane] = m0; mb[wv][64 + lane] = m1;
    __syncthreads();
    float o = b2[lane];
    #pragma unroll 8
    for (int t = 0; t < 128; ++t)
        o = fmaf(mb[wv][t], w2[t * 64 + lane], o);
    const float snv = hn + o;
    slots[r * 64 + lane] = snv;

    if (last) {
        out[r * 64 + lane] = snv;
    } else {
        slot_ln_q_kq(snv, wv, lane, r, &scr[wv][0], wkT, lsg, lsb, Wq, lig, lib, gkq, aux);
    }
}

// ---------------------------------------------------------------------------
extern "C" void kernel_launch(void* const* d_in, const int* in_sizes, int n_in,
                              void* d_out, int out_size, void* d_ws, size_t ws_size,
                              hipStream_t stream)
{
    const float* x   = (const float*)d_in[0];
    const float* lig = (const float*)d_in[1];
    const float* lib = (const float*)d_in[2];
    const float* lsg = (const float*)d_in[3];
    const float* lsb = (const float*)d_in[4];
    const float* s0  = (const float*)d_in[5];
    const float* Wk  = (const float*)d_in[6];
    const float* Wv  = (const float*)d_in[7];
    const float* Wq  = (const float*)d_in[8];
    const float* wih = (const float*)d_in[9];
    const float* whh = (const float*)d_in[10];
    const float* bih = (const float*)d_in[11];
    const float* bhh = (const float*)d_in[12];
    const float* w1  = (const float*)d_in[13];
    const float* b1  = (const float*)d_in[14];
    const float* w2  = (const float*)d_in[15];
    const float* b2  = (const float*)d_in[16];

    // workspace (floats): gkq 28672 | aux 896 | slots 28672 | Y 458752 | zc 57344
    float* f = (float*)d_ws;
    float* gkq   = f; f += 448 * 64;
    float* aux   = f; f += 448 * 2;
    float* slots = f; f += 448 * 64;
    float* Y     = f; f += (long)64 * 16 * 448;
    float* zc    = f; f += (long)64 * 64 * 7 * 2;

    init_kernel<<<112, 256, 0, stream>>>(s0, lsg, lsb, Wq, Wk, lig, lib,
                                         slots, gkq, aux);
    for (int it = 0; it < 3; ++it) {
        attn_kernel<<<1024, 256, 0, stream>>>(x, gkq, aux, Y, zc);
        update_kernel<<<112, 256, 0, stream>>>(
            Y, zc, slots, Wv, wih, whh, bih, bhh, w1, b1, w2, b2,
            lsg, lsb, Wq, Wk, lig, lib, gkq, aux,
            (float*)d_out, it == 2);
    }
}

// Round 4
// 236.843 us; speedup vs baseline: 1.2341x; 1.2341x over previous
//
#include <hip/hip_runtime.h>
#include <stdint.h>

#define L2E 1.44269504088896f

static __device__ __forceinline__ float wsum(float v) {
    #pragma unroll
    for (int m = 1; m < 64; m <<= 1) v += __shfl_xor(v, m, 64);
    return v;
}
static __device__ __forceinline__ float sigm(float x) {
    return 1.0f / (1.0f + __builtin_amdgcn_exp2f(-x * L2E));
}
static __device__ __forceinline__ float tanh_(float x) {
    const float ax = fabsf(x);
    const float t = __builtin_amdgcn_exp2f(-2.0f * ax * L2E);
    const float r = (1.0f - t) / (1.0f + t);
    return (x < 0.f) ? -r : r;
}

// ---------------------------------------------------------------------------
// transpose: wihT[i*192+j]=wih[j*64+i]; whhT same; WkT[p*64+d]=Wk[d*64+p].
// grid 112 x 256 = 28672 threads = exactly 12288+12288+4096 elements.
// ---------------------------------------------------------------------------
__global__ __launch_bounds__(256) void transpose_kernel(
    const float* __restrict__ wih, const float* __restrict__ whh,
    const float* __restrict__ Wk,
    float* __restrict__ wihT, float* __restrict__ whhT, float* __restrict__ WkT)
{
    const int idx = blockIdx.x * 256 + threadIdx.x;
    if (idx < 12288) {
        const int i = idx / 192, j = idx - i * 192;
        wihT[idx] = wih[j * 64 + i];
    } else if (idx < 24576) {
        const int o = idx - 12288;
        const int i = o / 192, j = o - i * 192;
        whhT[o] = whh[j * 64 + i];
    } else {
        const int o = idx - 24576;
        const int p = o >> 6, d = o & 63;
        WkT[o] = Wk[d * 64 + p];
    }
}

// ---------------------------------------------------------------------------
// Slot-side tail (init only): LN(slot) -> q=sn@Wq*0.125 -> kq=Wk@q ->
// gkq = ln_inp_g*kq, aux = (sum g*kq, sum b*kq). One wave per (b,s).
// ---------------------------------------------------------------------------
static __device__ __forceinline__ void slot_ln_q_kq(
    float snv, int wv, int lane, int r,
    float* scr, const float* wkT,
    const float* lsg, const float* lsb, const float* Wq,
    const float* lig, const float* lib,
    float* __restrict__ gkq, float* __restrict__ aux)
{
    const float mean = wsum(snv) * (1.0f / 64.0f);
    const float d = snv - mean;
    const float var = wsum(d * d) * (1.0f / 64.0f);
    const float rs = rsqrtf(var + 1e-5f);
    const float sn = d * rs * lsg[lane] + lsb[lane];
    __syncthreads();
    scr[lane] = sn;
    __syncthreads();
    float q = 0.f;
    #pragma unroll 8
    for (int i = 0; i < 64; ++i) q = fmaf(scr[i], Wq[i * 64 + lane], q);
    q *= 0.125f;
    __syncthreads();
    scr[lane] = q;
    __syncthreads();
    float kq = 0.f;
    #pragma unroll 8
    for (int p = 0; p < 64; ++p) kq = fmaf(wkT[p * 64 + lane], scr[p], kq);
    const float bk = wsum(lib[lane] * kq);
    const float gk = lig[lane] * kq;
    const float g1 = wsum(gk);
    gkq[r * 64 + lane] = gk;
    if (lane == 0) { aux[r * 2] = g1; aux[r * 2 + 1] = bk; }
}

__global__ __launch_bounds__(256) void init_kernel(
    const float* __restrict__ s0,
    const float* __restrict__ lsg, const float* __restrict__ lsb,
    const float* __restrict__ Wq,  const float* __restrict__ Wk,
    const float* __restrict__ lig, const float* __restrict__ lib,
    float* __restrict__ slots, float* __restrict__ gkq, float* __restrict__ aux)
{
    __shared__ float wkT[4096];
    __shared__ float scr[4][64];
    const int tid = threadIdx.x, lane = tid & 63, wv = tid >> 6;
    const int r = blockIdx.x * 4 + wv;
    const int s = r % 7;
    #pragma unroll
    for (int i = tid; i < 4096; i += 256) {
        const int d = i >> 6, p = i & 63;
        wkT[p * 64 + d] = Wk[i];
    }
    const float h = s0[s * 64 + lane];
    slots[r * 64 + lane] = h;
    __syncthreads();
    slot_ln_q_kq(h, wv, lane, r, &scr[wv][0], wkT, lsg, lsb, Wq, lig, lib, gkq, aux);
}

// ---------------------------------------------------------------------------
// attn v2: per wave, two 32-row passes. Coalesced global->LDS x staging
// (pad 65: <=2-way bank aliasing everywhere). Phase A: 2 lanes/row, 32 dims
// each, one shfl_xor(32) combine; softmax; w*rs -> wsh. Phase B: reads x and
// wsh from LDS, accumulates Y[14]/lane. Block reduce -> Ypart[b][chunk][456]
// (448 Y + 7 colsums + pad). Z is NOT stored (Z = sum_d Y / 64 in update).
// grid B*16 = 1024 x 256.
// ---------------------------------------------------------------------------
__global__ __launch_bounds__(256) void attn_kernel(
    const float* __restrict__ x,
    const float* __restrict__ gkq, const float* __restrict__ aux,
    float* __restrict__ Ypart)
{
    __shared__ float xsh[4][32 * 65];
    __shared__ float wsh[4][32][8];
    __shared__ float gkql[448];
    __shared__ float auxl[14];
    __shared__ float ybuf[4][456];
    const int tid = threadIdx.x, lane = tid & 63, wv = tid >> 6;
    const int b = blockIdx.x >> 4, chunk = blockIdx.x & 15;

    gkql[tid] = gkq[b * 448 + tid];
    if (tid < 192) gkql[tid + 256] = gkq[b * 448 + tid + 256];
    if (tid < 14) auxl[tid] = aux[b * 14 + tid];
    __syncthreads();

    const int q5 = lane & 31, h = lane >> 5;   // (row-in-pass, dim half)
    float Yr[14];
    #pragma unroll
    for (int i = 0; i < 14; ++i) Yr[i] = 0.f;
    float cacc[7] = {0.f, 0.f, 0.f, 0.f, 0.f, 0.f, 0.f};

    const float* tbase = x + (((long)b * 4096) + chunk * 256 + wv * 64) * 64;
    #pragma unroll 1
    for (int pass = 0; pass < 2; ++pass) {
        // ---- coalesced stage: 32 rows x 64 dims -> LDS (pad 65) ----
        const float4* src = (const float4*)(tbase + pass * 2048);
        #pragma unroll
        for (int st = 0; st < 8; ++st) {
            const float4 d4 = src[st * 64 + lane];
            const int f = (st * 64 + lane) * 4;
            const int row = f >> 6, dim = f & 63;
            float* dst = &xsh[wv][row * 65 + dim];
            dst[0] = d4.x; dst[1] = d4.y; dst[2] = d4.z; dst[3] = d4.w;
        }
        // same-wave producer/consumer: compiler orders LDS ops, no barrier.

        // ---- Phase A: row = q5, dims h*32..h*32+31 ----
        float xf[32];
        float sum = 0.f, ss = 0.f;
        const float* xr = &xsh[wv][q5 * 65 + h * 32];
        #pragma unroll
        for (int c = 0; c < 32; ++c) {
            xf[c] = xr[c];
            sum += xf[c];
            ss = fmaf(xf[c], xf[c], ss);
        }
        float acc[7];
        #pragma unroll
        for (int s = 0; s < 7; ++s) {
            float a = 0.f;
            const float* gk = &gkql[s * 64 + h * 32];
            #pragma unroll
            for (int c = 0; c < 32; ++c) a = fmaf(xf[c], gk[c], a);
            acc[s] = a;
        }
        sum += __shfl_xor(sum, 32, 64);
        ss  += __shfl_xor(ss, 32, 64);
        #pragma unroll
        for (int s = 0; s < 7; ++s) acc[s] += __shfl_xor(acc[s], 32, 64);

        const float m   = sum * (1.0f / 64.0f);
        const float var = ss * (1.0f / 64.0f) - m * m;
        const float rs  = rsqrtf(var + 1e-5f);
        const float rsm = rs * m;
        float t[7];
        #pragma unroll
        for (int s = 0; s < 7; ++s)
            t[s] = fmaf(rs, acc[s], fmaf(-rsm, auxl[2 * s], auxl[2 * s + 1]));
        float mx = t[0];
        #pragma unroll
        for (int s = 1; s < 7; ++s) mx = fmaxf(mx, t[s]);
        float e[7], se = 0.f;
        #pragma unroll
        for (int s = 0; s < 7; ++s) {
            e[s] = __builtin_amdgcn_exp2f((t[s] - mx) * L2E);
            se += e[s];
        }
        const float inv = 1.0f / se;
        #pragma unroll
        for (int s = 0; s < 7; ++s) {
            const float w = fmaf(e[s], inv, 1e-8f);
            cacc[s] += w;                       // both halves: x2, fixed below
            if (h == 0) wsh[wv][q5][s] = w * rs;
        }
        if (h == 0) wsh[wv][q5][7] = 0.f;

        // ---- Phase B: rr = 2*step+h rows, dims q5*2, q5*2+1 ----
        #pragma unroll 4
        for (int r2 = 0; r2 < 16; ++r2) {
            const int rr = r2 * 2 + h;
            const float4 p0 = *(const float4*)&wsh[wv][rr][0];
            const float4 p1 = *(const float4*)&wsh[wv][rr][4];
            const float v0 = xsh[wv][rr * 65 + q5 * 2];
            const float v1 = xsh[wv][rr * 65 + q5 * 2 + 1];
            const float ps[7] = {p0.x, p0.y, p0.z, p0.w, p1.x, p1.y, p1.z};
            #pragma unroll
            for (int s = 0; s < 7; ++s) {
                Yr[2 * s]     = fmaf(ps[s], v0, Yr[2 * s]);
                Yr[2 * s + 1] = fmaf(ps[s], v1, Yr[2 * s + 1]);
            }
        }
    }

    // ---- wave reduce + block reduce -> Ypart ----
    #pragma unroll
    for (int i = 0; i < 14; ++i) Yr[i] += __shfl_xor(Yr[i], 32, 64);
    if (h == 0) {
        #pragma unroll
        for (int s = 0; s < 7; ++s) {
            ybuf[wv][s * 64 + q5 * 2]     = Yr[2 * s];
            ybuf[wv][s * 64 + q5 * 2 + 1] = Yr[2 * s + 1];
        }
    }
    #pragma unroll
    for (int s = 0; s < 7; ++s) {
        const float Cs = wsum(cacc[s]) * 0.5f;   // each row counted twice
        if (lane == 0) ybuf[wv][448 + s] = Cs;
    }
    if (lane == 1) ybuf[wv][455] = 0.f;
    __syncthreads();
    for (int i = tid; i < 456; i += 256)
        Ypart[((long)b * 16 + chunk) * 456 + i] =
            ybuf[0][i] + ybuf[1][i] + ybuf[2][i] + ybuf[3][i];
}

// ---------------------------------------------------------------------------
// update v2: one block (256 thr) per (b,s) row. All weight reads coalesced
// (wihT/whhT/WkT pre-transposed). Chain: Y/C reduce -> aoc -> u=(aoc@Wv) ->
// GRU -> MLP -> slots (+ next-iter LN/q/kq or final store). grid 448.
// ---------------------------------------------------------------------------
__global__ __launch_bounds__(256) void update_kernel(
    const float* __restrict__ Ypart, float* __restrict__ slots,
    const float* __restrict__ Wv,
    const float* __restrict__ wihT, const float* __restrict__ whhT,
    const float* __restrict__ bih,  const float* __restrict__ bhh,
    const float* __restrict__ w1,   const float* __restrict__ b1,
    const float* __restrict__ w2,   const float* __restrict__ b2,
    const float* __restrict__ lsg,  const float* __restrict__ lsb,
    const float* __restrict__ Wq,   const float* __restrict__ WkT,
    const float* __restrict__ lig,  const float* __restrict__ lib,
    float* __restrict__ gkq, float* __restrict__ aux,
    float* __restrict__ out, int last)
{
    __shared__ float red[4][64];
    __shared__ float c16[16];
    __shared__ float ash[64];
    __shared__ float ush[64];
    __shared__ float hsh[64];
    __shared__ float gish[192], ghsh[192];
    __shared__ float hnsh[64];
    __shared__ float mbsh[128];
    __shared__ float qsh[64];
    const int tid = threadIdx.x, lane = tid & 63, wv = tid >> 6;
    const int r = blockIdx.x;                   // 0..447
    const int b = r / 7, s = r - b * 7;
    const float* Yb = Ypart + (long)b * 16 * 456;

    // stage 1: Y partial sums (4 chunks per wave), colsum parts, h load
    float yp = 0.f;
    #pragma unroll
    for (int c = 0; c < 4; ++c)
        yp += Yb[(wv * 4 + c) * 456 + s * 64 + lane];
    red[wv][lane] = yp;
    if (tid < 16) c16[tid] = Yb[tid * 456 + 448 + s];
    if (tid >= 64 && tid < 128) hsh[tid - 64] = slots[r * 64 + (tid - 64)];
    __syncthreads();

    if (tid < 64) {                             // wave 0
        const float Yd = red[0][lane] + red[1][lane] + red[2][lane] + red[3][lane];
        float C = 0.f;
        #pragma unroll
        for (int c = 0; c < 16; ++c) C += c16[c];
        const float Z = wsum(Yd) * (1.0f / 64.0f);   // Z = sum_d Y / 64
        ash[lane] = (lig[lane] * (Yd - Z) + lib[lane] * C) / C;
    }
    __syncthreads();

    // stage 2: u = aoc @ Wv, i-split over 4 waves
    float up = 0.f;
    #pragma unroll
    for (int i = 0; i < 16; ++i) {
        const int ii = wv * 16 + i;
        up = fmaf(ash[ii], Wv[ii * 64 + lane], up);
    }
    red[wv][lane] = up;
    __syncthreads();
    if (tid < 64) ush[lane] = red[0][lane] + red[1][lane] + red[2][lane] + red[3][lane];
    __syncthreads();

    // stage 3: GRU gates (192 outputs, coalesced transposed weights)
    if (tid < 192) {
        float a1 = bih[tid], a2 = bhh[tid];
        #pragma unroll 8
        for (int i = 0; i < 64; ++i) {
            a1 = fmaf(ush[i], wihT[i * 192 + tid], a1);
            a2 = fmaf(hsh[i], whhT[i * 192 + tid], a2);
        }
        gish[tid] = a1; ghsh[tid] = a2;
    }
    __syncthreads();
    if (tid < 64) {
        const float rr = sigm(gish[tid] + ghsh[tid]);
        const float zz = sigm(gish[64 + tid] + ghsh[64 + tid]);
        const float nn = tanh_(gish[128 + tid] + rr * ghsh[128 + tid]);
        hnsh[tid] = (1.f - zz) * nn + zz * hsh[tid];
    }
    __syncthreads();

    // stage 4: MLP hidden (128 outputs)
    if (tid < 128) {
        float m = b1[tid];
        #pragma unroll 8
        for (int i = 0; i < 64; ++i) m = fmaf(hnsh[i], w1[i * 128 + tid], m);
        mbsh[tid] = fmaxf(m, 0.f);
    }
    __syncthreads();

    // stage 5: MLP out + residual; tail (wave 0 only, no barriers needed)
    if (tid < 64) {
        float o = b2[tid];
        #pragma unroll 8
        for (int t = 0; t < 128; ++t) o = fmaf(mbsh[t], w2[t * 64 + tid], o);
        const float snv = hnsh[tid] + o;
        slots[r * 64 + tid] = snv;
        if (last) {
            out[r * 64 + tid] = snv;
        } else {
            const float mean = wsum(snv) * (1.0f / 64.0f);
            const float d = snv - mean;
            const float var = wsum(d * d) * (1.0f / 64.0f);
            const float rs = rsqrtf(var + 1e-5f);
            const float sn = d * rs * lsg[tid] + lsb[tid];
            ash[tid] = sn;                       // wave0-internal reuse
            float q = 0.f;
            #pragma unroll 8
            for (int i = 0; i < 64; ++i) q = fmaf(ash[i], Wq[i * 64 + tid], q);
            qsh[tid] = q * 0.125f;
            float kq = 0.f;
            #pragma unroll 8
            for (int p = 0; p < 64; ++p) kq = fmaf(WkT[p * 64 + tid], qsh[p], kq);
            const float bk = wsum(lib[tid] * kq);
            const float gk = lig[tid] * kq;
            const float g1 = wsum(gk);
            gkq[r * 64 + tid] = gk;
            if (tid == 0) { aux[r * 2] = g1; aux[r * 2 + 1] = bk; }
        }
    }
}

// ---------------------------------------------------------------------------
extern "C" void kernel_launch(void* const* d_in, const int* in_sizes, int n_in,
                              void* d_out, int out_size, void* d_ws, size_t ws_size,
                              hipStream_t stream)
{
    const float* x   = (const float*)d_in[0];
    const float* lig = (const float*)d_in[1];
    const float* lib = (const float*)d_in[2];
    const float* lsg = (const float*)d_in[3];
    const float* lsb = (const float*)d_in[4];
    const float* s0  = (const float*)d_in[5];
    const float* Wk  = (const float*)d_in[6];
    const float* Wv  = (const float*)d_in[7];
    const float* Wq  = (const float*)d_in[8];
    const float* wih = (const float*)d_in[9];
    const float* whh = (const float*)d_in[10];
    const float* bih = (const float*)d_in[11];
    const float* bhh = (const float*)d_in[12];
    const float* w1  = (const float*)d_in[13];
    const float* b1  = (const float*)d_in[14];
    const float* w2  = (const float*)d_in[15];
    const float* b2  = (const float*)d_in[16];

    float* f = (float*)d_ws;
    float* gkq   = f; f += 448 * 64;
    float* aux   = f; f += 448 * 2;
    float* slots = f; f += 448 * 64;
    float* Ypart = f; f += (long)64 * 16 * 456;
    float* wihT  = f; f += 64 * 192;
    float* whhT  = f; f += 64 * 192;
    float* WkT   = f; f += 64 * 64;

    transpose_kernel<<<112, 256, 0, stream>>>(wih, whh, Wk, wihT, whhT, WkT);
    init_kernel<<<112, 256, 0, stream>>>(s0, lsg, lsb, Wq, Wk, lig, lib,
                                         slots, gkq, aux);
    for (int it = 0; it < 3; ++it) {
        attn_kernel<<<1024, 256, 0, stream>>>(x, gkq, aux, Ypart);
        update_kernel<<<448, 256, 0, stream>>>(
            Ypart, slots, Wv, wihT, whhT, bih, bhh, w1, b1, w2, b2,
            lsg, lsb, Wq, WkT, lig, lib, gkq, aux,
            (float*)d_out, it == 2);
    }
}